// Round 1
// baseline (1724.059 us; speedup 1.0000x reference)
//
#include <hip/hip_runtime.h>
#include <math.h>

#define H 128

// ---------------------------------------------------------------- degree ----
__global__ void k_deg_init(float* __restrict__ deg, int N) {
    int i = blockIdx.x * blockDim.x + threadIdx.x;
    if (i < N) deg[i] = 1.0f;  // self-loop contributes 1 to every node
}

__global__ void k_deg_count(const int* __restrict__ dst, float* __restrict__ deg, int E) {
    int e = blockIdx.x * blockDim.x + threadIdx.x;
    if (e < E) atomicAdd(&deg[dst[e]], 1.0f);
}

__global__ void k_dinv(const float* __restrict__ deg, float* __restrict__ dinv, int N) {
    int i = blockIdx.x * blockDim.x + threadIdx.x;
    if (i < N) dinv[i] = rsqrtf(deg[i]);  // deg >= 1 always (self loops)
}

// ------------------------------------------------- self-loop init of agg ----
// agg[n,:] = x[n,:] * dinv[n]^2   (fully initializes d_out; float4 per thread)
__global__ void k_self_init(const float* __restrict__ x, const float* __restrict__ dinv,
                            float* __restrict__ out, int N) {
    int t = blockIdx.x * blockDim.x + threadIdx.x;  // N * H/4 threads
    if (t >= N * (H / 4)) return;
    int n = t >> 5;  // t / (H/4) with H/4 == 32
    float s = dinv[n];
    s *= s;
    float4 v = ((const float4*)x)[t];
    v.x *= s; v.y *= s; v.z *= s; v.w *= s;
    ((float4*)out)[t] = v;
}

// ------------------------------------------------------- edge scatter-add ---
// one wave (64 lanes) per edge; lane handles 2 consecutive features
__global__ void k_scatter(const float* __restrict__ x, const int* __restrict__ ei,
                          const float* __restrict__ dinv, float* __restrict__ out, int E) {
    int gw = (blockIdx.x * blockDim.x + threadIdx.x) >> 6;
    int lane = threadIdx.x & 63;
    if (gw >= E) return;
    int s = ei[gw];
    int d = ei[E + gw];
    float nrm = dinv[s] * dinv[d];
    float2 v = ((const float2*)(x + (size_t)s * H))[lane];
    float* o = out + (size_t)d * H + 2 * lane;
    atomicAdd(o,     v.x * nrm);
    atomicAdd(o + 1, v.y * nrm);
}

// ------------------------------------- fused GEMM + bias + GELU + LayerNorm -
// io (= d_out) holds agg on entry; out = LN(GELU(agg @ W + b)) written in place.
// 256 threads = 4 waves; W staged in 64KB LDS; each wave computes 4 rows.
__global__ __launch_bounds__(256) void k_gemm_ln(float* __restrict__ io,
                                                 const float* __restrict__ W,
                                                 const float* __restrict__ bias,
                                                 const float* __restrict__ gamma,
                                                 const float* __restrict__ beta,
                                                 int N) {
    __shared__ float Ws[H * H];  // 64 KB
    {
        const float4* W4 = (const float4*)W;
        float4* S4 = (float4*)Ws;
        for (int i = threadIdx.x; i < H * H / 4; i += 256) S4[i] = W4[i];
    }
    __syncthreads();

    const int wave = threadIdx.x >> 6;
    const int lane = threadIdx.x & 63;
    const float2 b2  = ((const float2*)bias)[lane];
    const float2 g2  = ((const float2*)gamma)[lane];
    const float2 be2 = ((const float2*)beta)[lane];

    const int gw = blockIdx.x * 4 + wave;  // global wave id
    const int rows0 = gw * 4;
    if (rows0 >= N) return;

    // load 4 rows, each lane keeps its 2 features in registers
    float2 r[4];
#pragma unroll
    for (int i = 0; i < 4; ++i) {
        int rr = rows0 + i; if (rr >= N) rr = N - 1;
        r[i] = ((const float2*)(io + (size_t)rr * H))[lane];
    }

    float acc[4][2] = {{0.f,0.f},{0.f,0.f},{0.f,0.f},{0.f,0.f}};
#pragma unroll
    for (int k = 0; k < H; ++k) {
        float2 w2 = *(const float2*)&Ws[k * H + 2 * lane];
#pragma unroll
        for (int i = 0; i < 4; ++i) {
            float src = (k & 1) ? r[i].y : r[i].x;
            // k is a literal after unroll -> v_readlane broadcast (SGPR operand)
            float a = __uint_as_float(__builtin_amdgcn_readlane(__float_as_uint(src), k >> 1));
            acc[i][0] += a * w2.x;
            acc[i][1] += a * w2.y;
        }
    }

#pragma unroll
    for (int i = 0; i < 4; ++i) {
        int rr = rows0 + i;
        if (rr >= N) break;
        float v0 = acc[i][0] + b2.x;
        float v1 = acc[i][1] + b2.y;
        // exact GELU (erf form)
        v0 = 0.5f * v0 * (1.0f + erff(v0 * 0.70710678118654752f));
        v1 = 0.5f * v1 * (1.0f + erff(v1 * 0.70710678118654752f));
        // wave-wide LayerNorm reduction (64 lanes x 2 vals = 128 features)
        float s = v0 + v1;
        float q = v0 * v0 + v1 * v1;
#pragma unroll
        for (int off = 32; off > 0; off >>= 1) {
            s += __shfl_xor(s, off, 64);
            q += __shfl_xor(q, off, 64);
        }
        float mu  = s * (1.0f / H);
        float var = q * (1.0f / H) - mu * mu;
        float rs  = rsqrtf(var + 1e-5f);
        float o0 = (v0 - mu) * rs * g2.x + be2.x;
        float o1 = (v1 - mu) * rs * g2.y + be2.y;
        ((float2*)(io + (size_t)rr * H))[lane] = make_float2(o0, o1);
    }
}

// ---------------------------------------------------------------- launch ----
extern "C" void kernel_launch(void* const* d_in, const int* in_sizes, int n_in,
                              void* d_out, int out_size, void* d_ws, size_t ws_size,
                              hipStream_t stream) {
    const float* x     = (const float*)d_in[0];
    const int*   ei    = (const int*)d_in[1];
    const float* W     = (const float*)d_in[2];
    const float* b     = (const float*)d_in[3];
    const float* gamma = (const float*)d_in[4];
    const float* beta  = (const float*)d_in[5];
    float* out = (float*)d_out;

    const int N = in_sizes[0] / H;
    const int E = in_sizes[1] / 2;

    float* deg  = (float*)d_ws;  // N floats
    float* dinv = deg + N;       // N floats

    k_deg_init<<<(N + 255) / 256, 256, 0, stream>>>(deg, N);
    k_deg_count<<<(E + 255) / 256, 256, 0, stream>>>(ei + E, deg, E);
    k_dinv<<<(N + 255) / 256, 256, 0, stream>>>(deg, dinv, N);
    k_self_init<<<(N * (H / 4) + 255) / 256, 256, 0, stream>>>(x, dinv, out, N);
    k_scatter<<<(E + 3) / 4, 256, 0, stream>>>(x, ei, dinv, out, E);

    const int waves  = (N + 3) / 4;       // 4 rows per wave
    const int blocks = (waves + 3) / 4;   // 4 waves per block
    k_gemm_ln<<<blocks, 256, 0, stream>>>(out, W, b, gamma, beta, N);
}

// Round 2
// 683.783 us; speedup vs baseline: 2.5214x; 2.5214x over previous
//
#include <hip/hip_runtime.h>
#include <math.h>

#define H 128

// ------------------------------------------------------------- CSR build ----
__global__ void k_zero(int* __restrict__ p, int n) {
    int i = blockIdx.x * blockDim.x + threadIdx.x;
    if (i < n) p[i] = 0;
}

__global__ void k_hist(const int* __restrict__ dst, int* __restrict__ cnt, int E) {
    int e = blockIdx.x * blockDim.x + threadIdx.x;
    if (e < E) atomicAdd(&cnt[dst[e]], 1);
}

// per-block exclusive scan of cnt -> rowp (block-local), block totals -> bsum
__global__ __launch_bounds__(256) void k_scan1(const int* __restrict__ cnt,
                                               int* __restrict__ rowp,
                                               int* __restrict__ bsum, int N) {
    __shared__ int tmp[256];
    int t = threadIdx.x;
    int i = blockIdx.x * 256 + t;
    int v = (i < N) ? cnt[i] : 0;
    tmp[t] = v;
    __syncthreads();
#pragma unroll
    for (int off = 1; off < 256; off <<= 1) {
        int a = (t >= off) ? tmp[t - off] : 0;
        __syncthreads();
        tmp[t] += a;
        __syncthreads();
    }
    if (i < N) rowp[i] = tmp[t] - v;          // exclusive within block
    if (t == 255) bsum[blockIdx.x] = tmp[255];
}

// serial exclusive scan of block sums (nb ~ 391, negligible)
__global__ void k_scan2(int* __restrict__ bsum, int nb) {
    if (threadIdx.x == 0 && blockIdx.x == 0) {
        int run = 0;
        for (int i = 0; i < nb; ++i) { int v = bsum[i]; bsum[i] = run; run += v; }
    }
}

// add block offsets; init cursor; dinv = rsqrt(deg) with deg = cnt+1 (self loop)
__global__ void k_scan3(int* __restrict__ rowp, const int* __restrict__ bsum,
                        int* __restrict__ cursor, const int* __restrict__ cnt,
                        float* __restrict__ dinv, int N, int E) {
    int i = blockIdx.x * blockDim.x + threadIdx.x;
    if (i >= N) return;
    int r = rowp[i] + bsum[i >> 8];
    rowp[i] = r;
    cursor[i] = r;
    dinv[i] = rsqrtf((float)(cnt[i] + 1));
    if (i == 0) rowp[N] = E;
}

__global__ void k_place(const int* __restrict__ ei, int* __restrict__ cursor,
                        int* __restrict__ ssrc, int E) {
    int e = blockIdx.x * blockDim.x + threadIdx.x;
    if (e >= E) return;
    int s = ei[e];
    int d = ei[E + e];
    int pos = atomicAdd(&cursor[d], 1);
    ssrc[pos] = s;
}

// ------------------------------------------------------ gather aggregate ----
// one wave per node: out[n] = dinv[n] * ( dinv[n]*x[n] + sum_e dinv[s]*x[s] )
__global__ __launch_bounds__(256) void k_agg(const float* __restrict__ x,
                                             const int* __restrict__ rowp,
                                             const int* __restrict__ ssrc,
                                             const float* __restrict__ dinv,
                                             float* __restrict__ out, int N) {
    int n = blockIdx.x * 4 + (threadIdx.x >> 6);
    if (n >= N) return;
    int lane = threadIdx.x & 63;

    int lo = __builtin_amdgcn_readfirstlane(rowp[n]);
    int hi = __builtin_amdgcn_readfirstlane(rowp[n + 1]);
    float dn = dinv[n];

    const float2* x2 = (const float2*)x;
    float2 a = x2[(size_t)n * 64 + lane];
    float accx = a.x * dn, accy = a.y * dn;

    int j = lo;
    for (; j + 2 <= hi; j += 2) {
        int s0 = __builtin_amdgcn_readfirstlane(ssrc[j]);
        int s1 = __builtin_amdgcn_readfirstlane(ssrc[j + 1]);
        float d0 = dinv[s0];
        float d1 = dinv[s1];
        float2 v0 = x2[(size_t)s0 * 64 + lane];
        float2 v1 = x2[(size_t)s1 * 64 + lane];
        accx += v0.x * d0 + v1.x * d1;
        accy += v0.y * d0 + v1.y * d1;
    }
    if (j < hi) {
        int s0 = __builtin_amdgcn_readfirstlane(ssrc[j]);
        float d0 = dinv[s0];
        float2 v0 = x2[(size_t)s0 * 64 + lane];
        accx += v0.x * d0;
        accy += v0.y * d0;
    }
    ((float2*)out)[(size_t)n * 64 + lane] = make_float2(accx * dn, accy * dn);
}

// ------------------------------------- fused GEMM + bias + GELU + LayerNorm -
__global__ __launch_bounds__(256) void k_gemm_ln(float* __restrict__ io,
                                                 const float* __restrict__ W,
                                                 const float* __restrict__ bias,
                                                 const float* __restrict__ gamma,
                                                 const float* __restrict__ beta,
                                                 int N) {
    __shared__ float Ws[H * H];  // 64 KB
    {
        const float4* W4 = (const float4*)W;
        float4* S4 = (float4*)Ws;
        for (int i = threadIdx.x; i < H * H / 4; i += 256) S4[i] = W4[i];
    }
    __syncthreads();

    const int wave = threadIdx.x >> 6;
    const int lane = threadIdx.x & 63;
    const float2 b2  = ((const float2*)bias)[lane];
    const float2 g2  = ((const float2*)gamma)[lane];
    const float2 be2 = ((const float2*)beta)[lane];

    const int gw = blockIdx.x * 4 + wave;
    const int rows0 = gw * 4;
    if (rows0 >= N) return;

    float2 r[4];
#pragma unroll
    for (int i = 0; i < 4; ++i) {
        int rr = rows0 + i; if (rr >= N) rr = N - 1;
        r[i] = ((const float2*)(io + (size_t)rr * H))[lane];
    }

    float acc[4][2] = {{0.f,0.f},{0.f,0.f},{0.f,0.f},{0.f,0.f}};
#pragma unroll
    for (int k = 0; k < H; ++k) {
        float2 w2 = *(const float2*)&Ws[k * H + 2 * lane];
#pragma unroll
        for (int i = 0; i < 4; ++i) {
            float src = (k & 1) ? r[i].y : r[i].x;
            float a = __uint_as_float(__builtin_amdgcn_readlane(__float_as_uint(src), k >> 1));
            acc[i][0] += a * w2.x;
            acc[i][1] += a * w2.y;
        }
    }

#pragma unroll
    for (int i = 0; i < 4; ++i) {
        int rr = rows0 + i;
        if (rr >= N) break;
        float v0 = acc[i][0] + b2.x;
        float v1 = acc[i][1] + b2.y;
        v0 = 0.5f * v0 * (1.0f + erff(v0 * 0.70710678118654752f));
        v1 = 0.5f * v1 * (1.0f + erff(v1 * 0.70710678118654752f));
        float s = v0 + v1;
        float q = v0 * v0 + v1 * v1;
#pragma unroll
        for (int off = 32; off > 0; off >>= 1) {
            s += __shfl_xor(s, off, 64);
            q += __shfl_xor(q, off, 64);
        }
        float mu  = s * (1.0f / H);
        float var = q * (1.0f / H) - mu * mu;
        float rs  = rsqrtf(var + 1e-5f);
        float o0 = (v0 - mu) * rs * g2.x + be2.x;
        float o1 = (v1 - mu) * rs * g2.y + be2.y;
        ((float2*)(io + (size_t)rr * H))[lane] = make_float2(o0, o1);
    }
}

// ---------------------------------------------------------------- launch ----
extern "C" void kernel_launch(void* const* d_in, const int* in_sizes, int n_in,
                              void* d_out, int out_size, void* d_ws, size_t ws_size,
                              hipStream_t stream) {
    const float* x     = (const float*)d_in[0];
    const int*   ei    = (const int*)d_in[1];
    const float* W     = (const float*)d_in[2];
    const float* b     = (const float*)d_in[3];
    const float* gamma = (const float*)d_in[4];
    const float* beta  = (const float*)d_in[5];
    float* out = (float*)d_out;

    const int N = in_sizes[0] / H;
    const int E = in_sizes[1] / 2;
    const int nb = (N + 255) / 256;

    // workspace layout (all 4-byte elems)
    int*   cnt    = (int*)d_ws;              // N
    float* dinv   = (float*)(cnt + N);       // N
    int*   rowp   = (int*)(dinv + N);        // N+1
    int*   cursor = rowp + (N + 1);          // N
    int*   ssrc   = cursor + N;              // E
    int*   bsum   = ssrc + E;                // nb

    k_zero <<<(N + 255) / 256, 256, 0, stream>>>(cnt, N);
    k_hist <<<(E + 255) / 256, 256, 0, stream>>>(ei + E, cnt, E);
    k_scan1<<<nb, 256, 0, stream>>>(cnt, rowp, bsum, N);
    k_scan2<<<1, 64, 0, stream>>>(bsum, nb);
    k_scan3<<<(N + 255) / 256, 256, 0, stream>>>(rowp, bsum, cursor, cnt, dinv, N, E);
    k_place<<<(E + 255) / 256, 256, 0, stream>>>(ei, cursor, ssrc, E);

    k_agg  <<<(N + 3) / 4, 256, 0, stream>>>(x, rowp, ssrc, dinv, out, N);

    const int waves  = (N + 3) / 4;
    const int blocks = (waves + 3) / 4;
    k_gemm_ln<<<blocks, 256, 0, stream>>>(out, W, b, gamma, beta, N);
}

// Round 3
// 379.316 us; speedup vs baseline: 4.5452x; 1.8027x over previous
//
#include <hip/hip_runtime.h>
#include <math.h>

#define H 128

typedef __bf16 bf16x8 __attribute__((ext_vector_type(8)));
typedef float f32x4 __attribute__((ext_vector_type(4)));
typedef unsigned short u16x8 __attribute__((ext_vector_type(8)));

static __device__ __forceinline__ unsigned short f2bf(float f) {
    unsigned u = __float_as_uint(f);
    unsigned r = 0x7fffu + ((u >> 16) & 1u);
    return (unsigned short)((u + r) >> 16);
}

// ------------------------------------------------------------- CSR build ----
__global__ void k_zero(int* __restrict__ p, int n) {
    int i = blockIdx.x * blockDim.x + threadIdx.x;
    if (i < n) p[i] = 0;
}

__global__ void k_hist(const int* __restrict__ dst, int* __restrict__ cnt, int E) {
    int e = blockIdx.x * blockDim.x + threadIdx.x;
    if (e < E) atomicAdd(&cnt[dst[e]], 1);
}

__global__ __launch_bounds__(256) void k_scan1(const int* __restrict__ cnt,
                                               int* __restrict__ rowp,
                                               int* __restrict__ bsum, int N) {
    __shared__ int tmp[256];
    int t = threadIdx.x;
    int i = blockIdx.x * 256 + t;
    int v = (i < N) ? cnt[i] : 0;
    tmp[t] = v;
    __syncthreads();
#pragma unroll
    for (int off = 1; off < 256; off <<= 1) {
        int a = (t >= off) ? tmp[t - off] : 0;
        __syncthreads();
        tmp[t] += a;
        __syncthreads();
    }
    if (i < N) rowp[i] = tmp[t] - v;
    if (t == 255) bsum[blockIdx.x] = tmp[255];
}

__global__ void k_scan2(int* __restrict__ bsum, int nb) {
    if (threadIdx.x == 0 && blockIdx.x == 0) {
        int run = 0;
        for (int i = 0; i < nb; ++i) { int v = bsum[i]; bsum[i] = run; run += v; }
    }
}

__global__ void k_scan3(int* __restrict__ rowp, const int* __restrict__ bsum,
                        int* __restrict__ cursor, const int* __restrict__ cnt,
                        float* __restrict__ dinv, int N, int E) {
    int i = blockIdx.x * blockDim.x + threadIdx.x;
    if (i >= N) return;
    int r = rowp[i] + bsum[i >> 8];
    rowp[i] = r;
    cursor[i] = r;
    dinv[i] = rsqrtf((float)(cnt[i] + 1));
    if (i == 0) rowp[N] = E;
}

__global__ void k_place(const int* __restrict__ ei, int* __restrict__ cursor,
                        int* __restrict__ ssrc, int E) {
    int e = blockIdx.x * blockDim.x + threadIdx.x;
    if (e >= E) return;
    int s = ei[e];
    int d = ei[E + e];
    int pos = atomicAdd(&cursor[d], 1);
    ssrc[pos] = s;
}

// --------------------------------------------------- W transpose to bf16 ----
// Wt[j*128 + k] = bf16(W[k*128 + j])  (B^T form: k-contiguous per output col)
__global__ void k_wt(const float* __restrict__ W, unsigned short* __restrict__ Wt) {
    int t = blockIdx.x * 256 + threadIdx.x;   // 16384 threads
    int j = t >> 7, k = t & 127;
    Wt[(size_t)j * H + k] = f2bf(W[(size_t)k * H + j]);
}

// ------------------------------------------------------ gather aggregate ----
__global__ __launch_bounds__(256) void k_agg(const float* __restrict__ x,
                                             const int* __restrict__ rowp,
                                             const int* __restrict__ ssrc,
                                             const float* __restrict__ dinv,
                                             float* __restrict__ out, int N) {
    int n = blockIdx.x * 4 + (threadIdx.x >> 6);
    if (n >= N) return;
    int lane = threadIdx.x & 63;

    int lo = __builtin_amdgcn_readfirstlane(rowp[n]);
    int hi = __builtin_amdgcn_readfirstlane(rowp[n + 1]);
    float dn = dinv[n];

    const float2* x2 = (const float2*)x;
    float2 a = x2[(size_t)n * 64 + lane];
    float accx = a.x * dn, accy = a.y * dn;

    int j = lo;
    for (; j + 2 <= hi; j += 2) {
        int s0 = __builtin_amdgcn_readfirstlane(ssrc[j]);
        int s1 = __builtin_amdgcn_readfirstlane(ssrc[j + 1]);
        float d0 = dinv[s0];
        float d1 = dinv[s1];
        float2 v0 = x2[(size_t)s0 * 64 + lane];
        float2 v1 = x2[(size_t)s1 * 64 + lane];
        accx += v0.x * d0 + v1.x * d1;
        accy += v0.y * d0 + v1.y * d1;
    }
    if (j < hi) {
        int s0 = __builtin_amdgcn_readfirstlane(ssrc[j]);
        float d0 = dinv[s0];
        float2 v0 = x2[(size_t)s0 * 64 + lane];
        accx += v0.x * d0;
        accy += v0.y * d0;
    }
    ((float2*)out)[(size_t)n * 64 + lane] = make_float2(accx * dn, accy * dn);
}

// --------------------------- MFMA GEMM + bias + GELU + LayerNorm (in place) -
// 512 threads = 8 waves; 128 rows/block; each wave: 16 rows x 128 cols.
__global__ __launch_bounds__(512) void k_gemm_ln(float* __restrict__ io,
                                                 const unsigned short* __restrict__ Wt,
                                                 const float* __restrict__ bias,
                                                 const float* __restrict__ gamma,
                                                 const float* __restrict__ beta,
                                                 int N) {
    __shared__ unsigned short Ws[H * H];  // 32 KB, XOR-swizzled rows
    {
        const unsigned* src = (const unsigned*)Wt;  // 8192 u32 words
#pragma unroll
        for (int i = 0; i < 16; ++i) {
            int idx = threadIdx.x + i * 512;        // u32 index
            unsigned v = src[idx];
            int j = idx >> 6;                       // Wt row (output col)
            int byte = (idx << 2) ^ ((j & 7) << 4);
            *(unsigned*)((char*)Ws + byte) = v;
        }
    }
    __syncthreads();

    const int wv   = threadIdx.x >> 6;
    const int lane = threadIdx.x & 63;
    const int g    = lane >> 4;        // 0..3
    const int c    = lane & 15;        // 0..15
    const int r0   = blockIdx.x * 128 + wv * 16;
    if (r0 >= N) return;

    // per-lane column constants: cols ct*16 + c
    float bc[8], gc[8], bec[8];
#pragma unroll
    for (int ct = 0; ct < 8; ++ct) {
        int col = ct * 16 + c;
        bc[ct]  = bias[col];
        gc[ct]  = gamma[col];
        bec[ct] = beta[col];
    }

    f32x4 acc[8];
#pragma unroll
    for (int ct = 0; ct < 8; ++ct) acc[ct] = (f32x4){0.f, 0.f, 0.f, 0.f};

#pragma unroll
    for (int ks = 0; ks < 4; ++ks) {
        // A-frag: row = r0 + c, k = ks*32 + g*8 + e  (8 consecutive fp32)
        int ar = r0 + c; if (ar >= N) ar = N - 1;
        const float* ap = io + (size_t)ar * H + ks * 32 + g * 8;
        float4 a0 = *(const float4*)ap;
        float4 a1 = *(const float4*)(ap + 4);
        u16x8 ua;
        ua[0] = f2bf(a0.x); ua[1] = f2bf(a0.y); ua[2] = f2bf(a0.z); ua[3] = f2bf(a0.w);
        ua[4] = f2bf(a1.x); ua[5] = f2bf(a1.y); ua[6] = f2bf(a1.z); ua[7] = f2bf(a1.w);
        bf16x8 af = __builtin_bit_cast(bf16x8, ua);
#pragma unroll
        for (int ct = 0; ct < 8; ++ct) {
            // B-frag: col j = ct*16 + c, k = ks*32 + g*8 + e
            int j = ct * 16 + c;
            int byte = (j * 256 + ks * 64 + g * 16) ^ ((j & 7) << 4);
            bf16x8 bf = *(const bf16x8*)((const char*)Ws + byte);  // ds_read_b128
            acc[ct] = __builtin_amdgcn_mfma_f32_16x16x32_bf16(af, bf, acc[ct], 0, 0, 0);
        }
    }

    // epilogue: C[row = r0 + 4g + q][col = ct*16 + c] = acc[ct][q]
#pragma unroll
    for (int q = 0; q < 4; ++q) {
        int row = r0 + g * 4 + q;
        float v[8];
        float s = 0.f, sq = 0.f;
#pragma unroll
        for (int ct = 0; ct < 8; ++ct) {
            float t = acc[ct][q] + bc[ct];
            t = 0.5f * t * (1.0f + erff(t * 0.70710678118654752f));
            v[ct] = t;
            s += t;
            sq += t * t;
        }
        // reduce across the 16 lanes holding this row (lane bits 0..3)
#pragma unroll
        for (int off = 8; off > 0; off >>= 1) {
            s  += __shfl_xor(s,  off, 64);
            sq += __shfl_xor(sq, off, 64);
        }
        float mu  = s * (1.0f / H);
        float var = sq * (1.0f / H) - mu * mu;
        float rs  = rsqrtf(var + 1e-5f);
        if (row < N) {
            float* op = io + (size_t)row * H;
#pragma unroll
            for (int ct = 0; ct < 8; ++ct) {
                op[ct * 16 + c] = (v[ct] - mu) * rs * gc[ct] + bec[ct];
            }
        }
    }
}

// ---------------------------------------------------------------- launch ----
extern "C" void kernel_launch(void* const* d_in, const int* in_sizes, int n_in,
                              void* d_out, int out_size, void* d_ws, size_t ws_size,
                              hipStream_t stream) {
    const float* x     = (const float*)d_in[0];
    const int*   ei    = (const int*)d_in[1];
    const float* W     = (const float*)d_in[2];
    const float* b     = (const float*)d_in[3];
    const float* gamma = (const float*)d_in[4];
    const float* beta  = (const float*)d_in[5];
    float* out = (float*)d_out;

    const int N = in_sizes[0] / H;
    const int E = in_sizes[1] / 2;
    const int nb = (N + 255) / 256;

    // workspace layout (4-byte elems unless noted)
    int*   cnt    = (int*)d_ws;                      // N
    float* dinv   = (float*)(cnt + N);               // N
    int*   rowp   = (int*)(dinv + N);                // N+1
    int*   cursor = rowp + (N + 1);                  // N
    int*   ssrc   = cursor + N;                      // E
    int*   bsum   = ssrc + E;                        // nb
    unsigned short* Wt = (unsigned short*)(bsum + nb);  // H*H u16 (32 KB)

    k_wt   <<<(H * H) / 256, 256, 0, stream>>>(W, Wt);

    k_zero <<<(N + 255) / 256, 256, 0, stream>>>(cnt, N);
    k_hist <<<(E + 255) / 256, 256, 0, stream>>>(ei + E, cnt, E);
    k_scan1<<<nb, 256, 0, stream>>>(cnt, rowp, bsum, N);
    k_scan2<<<1, 64, 0, stream>>>(bsum, nb);
    k_scan3<<<(N + 255) / 256, 256, 0, stream>>>(rowp, bsum, cursor, cnt, dinv, N, E);
    k_place<<<(E + 255) / 256, 256, 0, stream>>>(ei, cursor, ssrc, E);

    k_agg  <<<(N + 3) / 4, 256, 0, stream>>>(x, rowp, ssrc, dinv, out, N);

    k_gemm_ln<<<(N + 127) / 128, 512, 0, stream>>>(out, Wt, b, gamma, beta, N);
}

// Round 4
// 342.624 us; speedup vs baseline: 5.0319x; 1.1071x over previous
//
#include <hip/hip_runtime.h>
#include <math.h>

#define H 128

typedef __bf16 bf16x8 __attribute__((ext_vector_type(8)));
typedef float f32x4 __attribute__((ext_vector_type(4)));

static __device__ __forceinline__ unsigned short f2bf(float f) {
    unsigned u = __float_as_uint(f);
    unsigned r = 0x7fffu + ((u >> 16) & 1u);
    return (unsigned short)((u + r) >> 16);
}
static __device__ __forceinline__ float bflo(unsigned w) {  // low bf16 -> f32
    return __uint_as_float(w << 16);
}
static __device__ __forceinline__ float bfhi(unsigned w) {  // high bf16 -> f32
    return __uint_as_float(w & 0xffff0000u);
}

// ------------------------------------------------------------- CSR build ----
__global__ void k_zero(int* __restrict__ p, int n) {
    int i = blockIdx.x * blockDim.x + threadIdx.x;
    if (i < n) p[i] = 0;
}

__global__ void k_hist(const int* __restrict__ dst, int* __restrict__ cnt, int E) {
    int e = blockIdx.x * blockDim.x + threadIdx.x;
    if (e < E) atomicAdd(&cnt[dst[e]], 1);
}

__global__ __launch_bounds__(256) void k_scan1(const int* __restrict__ cnt,
                                               int* __restrict__ rowp,
                                               int* __restrict__ bsum, int N) {
    __shared__ int tmp[256];
    int t = threadIdx.x;
    int i = blockIdx.x * 256 + t;
    int v = (i < N) ? cnt[i] : 0;
    tmp[t] = v;
    __syncthreads();
#pragma unroll
    for (int off = 1; off < 256; off <<= 1) {
        int a = (t >= off) ? tmp[t - off] : 0;
        __syncthreads();
        tmp[t] += a;
        __syncthreads();
    }
    if (i < N) rowp[i] = tmp[t] - v;
    if (t == 255) bsum[blockIdx.x] = tmp[255];
}

__global__ void k_scan2(int* __restrict__ bsum, int nb) {
    if (threadIdx.x == 0 && blockIdx.x == 0) {
        int run = 0;
        for (int i = 0; i < nb; ++i) { int v = bsum[i]; bsum[i] = run; run += v; }
    }
}

__global__ void k_scan3(int* __restrict__ rowp, const int* __restrict__ bsum,
                        int* __restrict__ cursor, const int* __restrict__ cnt,
                        float* __restrict__ dinv, int N, int E) {
    int i = blockIdx.x * blockDim.x + threadIdx.x;
    if (i >= N) return;
    int r = rowp[i] + bsum[i >> 8];
    rowp[i] = r;
    cursor[i] = r;
    dinv[i] = rsqrtf((float)(cnt[i] + 1));
    if (i == 0) rowp[N] = E;
}

__global__ void k_place(const int* __restrict__ ei, int* __restrict__ cursor,
                        int* __restrict__ ssrc, int E) {
    int e = blockIdx.x * blockDim.x + threadIdx.x;
    if (e >= E) return;
    int s = ei[e];
    int d = ei[E + e];
    int pos = atomicAdd(&cursor[d], 1);
    ssrc[pos] = s;
}

// --------------------------------------------------- W transpose to bf16 ----
__global__ void k_wt(const float* __restrict__ W, unsigned short* __restrict__ Wt) {
    int t = blockIdx.x * 256 + threadIdx.x;   // 16384 threads
    int j = t >> 7, k = t & 127;
    Wt[(size_t)j * H + k] = f2bf(W[(size_t)k * H + j]);
}

// ------------------------------------------- x pre-scale: xb = bf16(x*dinv) -
// xb2 is N*64 u32 words (bf16 pairs); each thread handles 4 feats.
__global__ void k_xb(const float* __restrict__ x, const float* __restrict__ dinv,
                     unsigned* __restrict__ xb2, int N) {
    int t = blockIdx.x * 256 + threadIdx.x;   // N*32 threads
    if (t >= N * 32) return;
    int n = t >> 5;
    float s = dinv[n];
    float4 v = ((const float4*)x)[t];
    uint2 o;
    o.x = (unsigned)f2bf(v.x * s) | ((unsigned)f2bf(v.y * s) << 16);
    o.y = (unsigned)f2bf(v.z * s) | ((unsigned)f2bf(v.w * s) << 16);
    ((uint2*)xb2)[t] = o;
}

// ------------------------------------------------------ gather aggregate ----
// one wave per node: aggb[n] = bf16( dinv[n] * (xb[n] + sum_e xb[src_e]) )
__global__ __launch_bounds__(256) void k_agg(const unsigned* __restrict__ xb2,
                                             const int* __restrict__ rowp,
                                             const int* __restrict__ ssrc,
                                             const float* __restrict__ dinv,
                                             unsigned* __restrict__ aggb2, int N) {
    int n = blockIdx.x * 4 + (threadIdx.x >> 6);
    if (n >= N) return;
    int lane = threadIdx.x & 63;

    int lo = __builtin_amdgcn_readfirstlane(rowp[n]);
    int hi = __builtin_amdgcn_readfirstlane(rowp[n + 1]);
    float dn = dinv[n];

    unsigned w = xb2[(size_t)n * 64 + lane];
    float accx = bflo(w), accy = bfhi(w);

    int j = lo;
    for (; j + 4 <= hi; j += 4) {
        int s0 = __builtin_amdgcn_readfirstlane(ssrc[j]);
        int s1 = __builtin_amdgcn_readfirstlane(ssrc[j + 1]);
        int s2 = __builtin_amdgcn_readfirstlane(ssrc[j + 2]);
        int s3 = __builtin_amdgcn_readfirstlane(ssrc[j + 3]);
        unsigned w0 = xb2[(size_t)s0 * 64 + lane];
        unsigned w1 = xb2[(size_t)s1 * 64 + lane];
        unsigned w2 = xb2[(size_t)s2 * 64 + lane];
        unsigned w3 = xb2[(size_t)s3 * 64 + lane];
        accx += bflo(w0) + bflo(w1) + bflo(w2) + bflo(w3);
        accy += bfhi(w0) + bfhi(w1) + bfhi(w2) + bfhi(w3);
    }
    for (; j < hi; ++j) {
        int s0 = __builtin_amdgcn_readfirstlane(ssrc[j]);
        unsigned w0 = xb2[(size_t)s0 * 64 + lane];
        accx += bflo(w0);
        accy += bfhi(w0);
    }
    aggb2[(size_t)n * 64 + lane] =
        (unsigned)f2bf(accx * dn) | ((unsigned)f2bf(accy * dn) << 16);
}

// --------------------------- MFMA GEMM + bias + GELU + LayerNorm ------------
// A = aggb (bf16), B = Wt staged in LDS (XOR swizzle), out fp32 to d_out.
__global__ __launch_bounds__(512) void k_gemm_ln(const unsigned short* __restrict__ aggb,
                                                 const unsigned short* __restrict__ Wt,
                                                 const float* __restrict__ bias,
                                                 const float* __restrict__ gamma,
                                                 const float* __restrict__ beta,
                                                 float* __restrict__ outp,
                                                 int N) {
    __shared__ unsigned short Ws[H * H];  // 32 KB, XOR-swizzled rows
    {
        const unsigned* src = (const unsigned*)Wt;  // 8192 u32 words
#pragma unroll
        for (int i = 0; i < 16; ++i) {
            int idx = threadIdx.x + i * 512;
            unsigned v = src[idx];
            int j = idx >> 6;
            int byte = (idx << 2) ^ ((j & 7) << 4);
            *(unsigned*)((char*)Ws + byte) = v;
        }
    }
    __syncthreads();

    const int wv   = threadIdx.x >> 6;
    const int lane = threadIdx.x & 63;
    const int g    = lane >> 4;
    const int c    = lane & 15;
    const int r0   = blockIdx.x * 128 + wv * 16;
    if (r0 >= N) return;

    float bc[8], gc[8], bec[8];
#pragma unroll
    for (int ct = 0; ct < 8; ++ct) {
        int col = ct * 16 + c;
        bc[ct]  = bias[col];
        gc[ct]  = gamma[col];
        bec[ct] = beta[col];
    }

    f32x4 acc[8];
#pragma unroll
    for (int ct = 0; ct < 8; ++ct) acc[ct] = (f32x4){0.f, 0.f, 0.f, 0.f};

#pragma unroll
    for (int ks = 0; ks < 4; ++ks) {
        int ar = r0 + c; if (ar >= N) ar = N - 1;
        bf16x8 af = *(const bf16x8*)(aggb + (size_t)ar * H + ks * 32 + g * 8);
#pragma unroll
        for (int ct = 0; ct < 8; ++ct) {
            int j = ct * 16 + c;
            int byte = (j * 256 + ks * 64 + g * 16) ^ ((j & 7) << 4);
            bf16x8 bf = *(const bf16x8*)((const char*)Ws + byte);
            acc[ct] = __builtin_amdgcn_mfma_f32_16x16x32_bf16(af, bf, acc[ct], 0, 0, 0);
        }
    }

#pragma unroll
    for (int q = 0; q < 4; ++q) {
        int row = r0 + g * 4 + q;
        float v[8];
        float s = 0.f, sq = 0.f;
#pragma unroll
        for (int ct = 0; ct < 8; ++ct) {
            float t = acc[ct][q] + bc[ct];
            t = 0.5f * t * (1.0f + erff(t * 0.70710678118654752f));
            v[ct] = t;
            s += t;
            sq += t * t;
        }
#pragma unroll
        for (int off = 8; off > 0; off >>= 1) {
            s  += __shfl_xor(s,  off, 64);
            sq += __shfl_xor(sq, off, 64);
        }
        float mu  = s * (1.0f / H);
        float var = sq * (1.0f / H) - mu * mu;
        float rs  = rsqrtf(var + 1e-5f);
        if (row < N) {
            float* op = outp + (size_t)row * H;
#pragma unroll
            for (int ct = 0; ct < 8; ++ct) {
                op[ct * 16 + c] = (v[ct] - mu) * rs * gc[ct] + bec[ct];
            }
        }
    }
}

// ---------------------------------------------------------------- launch ----
extern "C" void kernel_launch(void* const* d_in, const int* in_sizes, int n_in,
                              void* d_out, int out_size, void* d_ws, size_t ws_size,
                              hipStream_t stream) {
    const float* x     = (const float*)d_in[0];
    const int*   ei    = (const int*)d_in[1];
    const float* W     = (const float*)d_in[2];
    const float* b     = (const float*)d_in[3];
    const float* gamma = (const float*)d_in[4];
    const float* beta  = (const float*)d_in[5];
    float* out = (float*)d_out;

    const int N = in_sizes[0] / H;
    const int E = in_sizes[1] / 2;
    const int nb = (N + 255) / 256;

    // workspace layout (4-byte elems unless noted)
    int*   cnt    = (int*)d_ws;                         // N
    float* dinv   = (float*)(cnt + N);                  // N
    int*   rowp   = (int*)(dinv + N);                   // N+1
    int*   cursor = rowp + (N + 1);                     // N
    int*   ssrc   = cursor + N;                         // E
    int*   bsum   = ssrc + E;                           // nb
    unsigned short* Wt = (unsigned short*)(bsum + nb);  // H*H u16 (32 KB)
    unsigned* aggb2 = (unsigned*)(Wt + H * H);          // N*64 u32 (25.6 MB)

    // xb (bf16 pre-scaled x) lives in the FIRST HALF of d_out; it is fully
    // consumed by k_agg before k_gemm_ln overwrites d_out with the result.
    unsigned* xb2 = (unsigned*)d_out;                   // N*64 u32

    k_wt   <<<(H * H) / 256, 256, 0, stream>>>(W, Wt);

    k_zero <<<(N + 255) / 256, 256, 0, stream>>>(cnt, N);
    k_hist <<<(E + 255) / 256, 256, 0, stream>>>(ei + E, cnt, E);
    k_scan1<<<nb, 256, 0, stream>>>(cnt, rowp, bsum, N);
    k_scan2<<<1, 64, 0, stream>>>(bsum, nb);
    k_scan3<<<(N + 255) / 256, 256, 0, stream>>>(rowp, bsum, cursor, cnt, dinv, N, E);
    k_xb   <<<(N * 32 + 255) / 256, 256, 0, stream>>>(x, dinv, xb2, N);
    k_place<<<(E + 255) / 256, 256, 0, stream>>>(ei, cursor, ssrc, E);

    k_agg  <<<(N + 3) / 4, 256, 0, stream>>>(xb2, rowp, ssrc, dinv, aggb2, N);

    k_gemm_ln<<<(N + 127) / 128, 512, 0, stream>>>((const unsigned short*)aggb2, Wt,
                                                   b, gamma, beta, out, N);
}